// Round 1
// baseline (1326.391 us; speedup 1.0000x reference)
//
#include <hip/hip_runtime.h>

#define NBX 512
#define NBY 512
#define KNB 5
#define NMAP (NBX * NBY)
#define TARGET_AREA 0.9f

// One thread per node: compute 5 x-potentials and 5 y-potentials, scatter
// 25 atomic adds into a privatized density-map copy (blockIdx & copy_mask,
// which correlates with XCD via round-robin dispatch -> 8x less per-address
// contention).
__global__ __launch_bounds__(256) void density_scatter_kernel(
    const float* __restrict__ pos,
    const float* __restrict__ nsx, const float* __restrict__ nsy,
    const float* __restrict__ axp, const float* __restrict__ bxp, const float* __restrict__ cxp,
    const float* __restrict__ ayp, const float* __restrict__ byp, const float* __restrict__ cyp,
    float* __restrict__ maps, int n, int copy_mask)
{
    int i = blockIdx.x * blockDim.x + threadIdx.x;
    if (i >= n) return;

    float x  = pos[i],      y  = pos[n + i];
    float sx = nsx[i],      sy = nsy[i];
    float a_x = axp[i], b_x = bxp[i], c_x = cxp[i];
    float a_y = ayp[i], b_y = byp[i], c_y = cyp[i];

    float centerx = x + 0.5f * sx;
    float centery = y + 0.5f * sy;
    int startx = (int)floorf(x - 2.0f);
    startx = min(max(startx, 0), NBX - KNB);
    int starty = (int)floorf(y - 2.0f);
    starty = min(max(starty, 0), NBY - KNB);

    float p1x = 0.5f * sx + 1.0f, p2x = 0.5f * sx + 2.0f;
    float p1y = 0.5f * sy + 1.0f, p2y = 0.5f * sy + 2.0f;

    float px[KNB], py[KNB];
#pragma unroll
    for (int k = 0; k < KNB; ++k) {
        // bin_center[idx] = idx + 0.5 exactly (BIN=1, XL=0)
        float bc = (float)(startx + k) + 0.5f;
        float d  = fabsf(centerx - bc);
        float v1 = c_x * (1.0f - a_x * d * d);
        float dm = d - p2x;
        float v2 = (c_x * b_x) * dm * dm;
        px[k] = (d < p1x) ? v1 : ((d < p2x) ? v2 : 0.0f);
    }
#pragma unroll
    for (int k = 0; k < KNB; ++k) {
        float bc = (float)(starty + k) + 0.5f;
        float d  = fabsf(centery - bc);
        float v1 = c_y * (1.0f - a_y * d * d);
        float dm = d - p2y;
        float v2 = (c_y * b_y) * dm * dm;
        py[k] = (d < p1y) ? v1 : ((d < p2y) ? v2 : 0.0f);
    }

    float* map = maps + (size_t)(blockIdx.x & copy_mask) * NMAP;
#pragma unroll
    for (int kx = 0; kx < KNB; ++kx) {
        float vx = px[kx];
        int rowbase = (startx + kx) * NBY + starty;
#pragma unroll
        for (int ky = 0; ky < KNB; ++ky) {
            atomicAdd(&map[rowbase + ky], vx * py[ky]);
        }
    }
}

// Fold the privatized copies + initial map, compute sum((d - target)^2).
__global__ __launch_bounds__(256) void density_cost_kernel(
    const float* __restrict__ maps,
    const float* __restrict__ initial_map,
    float* __restrict__ out, int ncopies)
{
    float acc = 0.0f;
    int stride = gridDim.x * blockDim.x;
    for (int b = blockIdx.x * blockDim.x + threadIdx.x; b < NMAP; b += stride) {
        float d = initial_map[b];
        for (int c = 0; c < ncopies; ++c) d += maps[(size_t)c * NMAP + b];
        float delta = d - TARGET_AREA;
        acc += delta * delta;
    }
    // wave-64 butterfly reduce
#pragma unroll
    for (int off = 32; off > 0; off >>= 1)
        acc += __shfl_down(acc, off, 64);
    __shared__ float smem[4];
    int lane = threadIdx.x & 63;
    int wave = threadIdx.x >> 6;
    if (lane == 0) smem[wave] = acc;
    __syncthreads();
    if (threadIdx.x == 0) {
        float s = smem[0] + smem[1] + smem[2] + smem[3];
        atomicAdd(out, s);
    }
}

extern "C" void kernel_launch(void* const* d_in, const int* in_sizes, int n_in,
                              void* d_out, int out_size, void* d_ws, size_t ws_size,
                              hipStream_t stream) {
    const float* pos = (const float*)d_in[0];
    const float* nsx = (const float*)d_in[1];
    const float* nsy = (const float*)d_in[2];
    const float* axp = (const float*)d_in[3];
    const float* bxp = (const float*)d_in[4];
    const float* cxp = (const float*)d_in[5];
    const float* ayp = (const float*)d_in[6];
    const float* byp = (const float*)d_in[7];
    const float* cyp = (const float*)d_in[8];
    // d_in[9], d_in[10] = bin centers (computed analytically, unused)
    const float* initial_map = (const float*)d_in[11];

    int n = in_sizes[1];  // node count

    size_t mapbytes = (size_t)NMAP * sizeof(float);
    int copies = 1;
    while (copies < 8 && (size_t)(copies * 2) * mapbytes <= ws_size) copies <<= 1;

    hipMemsetAsync(d_ws, 0, (size_t)copies * mapbytes, stream);
    hipMemsetAsync(d_out, 0, sizeof(float), stream);

    int blocks = (n + 255) / 256;
    density_scatter_kernel<<<blocks, 256, 0, stream>>>(
        pos, nsx, nsy, axp, bxp, cxp, ayp, byp, cyp,
        (float*)d_ws, n, copies - 1);

    density_cost_kernel<<<256, 256, 0, stream>>>(
        (const float*)d_ws, initial_map, (float*)d_out, copies);
}

// Round 2
// 266.351 us; speedup vs baseline: 4.9799x; 4.9799x over previous
//
#include <hip/hip_runtime.h>

#define NBX 512
#define NBY 512
#define KNB 5
#define NMAP (NBX * NBY)
#define TARGET_AREA 0.9f

#define TSH 5               // log2(tile size in bins)
#define TS 32               // tile size (bins)
#define NTX 16
#define NTY 16
#define NT (NTX * NTY)      // 256 tiles
#define HALO 2
#define RDIM (TS + 2 * HALO)   // 36
#define RWORDS (RDIM * RDIM)   // 1296
#define BPT 8               // blocks per tile in accum phase

// ---------- shared per-node math ----------
__device__ __forceinline__ void compute_node(
    float x, float y, float sx, float sy,
    float a_x, float b_x, float c_x,
    float a_y, float b_y, float c_y,
    int& rsx, int& rsy, float* px, float* py)
{
    float ctrx = x + 0.5f * sx;
    float ctry = y + 0.5f * sy;
    rsx = min(max((int)floorf(x - 2.0f), 0), NBX - KNB);
    rsy = min(max((int)floorf(y - 2.0f), 0), NBY - KNB);
    float p1x = 0.5f * sx + 1.0f, p2x = 0.5f * sx + 2.0f;
    float p1y = 0.5f * sy + 1.0f, p2y = 0.5f * sy + 2.0f;
#pragma unroll
    for (int k = 0; k < KNB; ++k) {
        float d = fabsf(ctrx - ((float)(rsx + k) + 0.5f));   // bin_center = idx+0.5
        float dm = d - p2x;
        float v1 = c_x * (1.0f - a_x * d * d);
        float v2 = (c_x * b_x) * dm * dm;
        px[k] = (d < p1x) ? v1 : ((d < p2x) ? v2 : 0.0f);
    }
#pragma unroll
    for (int k = 0; k < KNB; ++k) {
        float d = fabsf(ctry - ((float)(rsy + k) + 0.5f));
        float dm = d - p2y;
        float v1 = c_y * (1.0f - a_y * d * d);
        float v2 = (c_y * b_y) * dm * dm;
        py[k] = (d < p1y) ? v1 : ((d < p2y) ? v2 : 0.0f);
    }
}

__device__ __forceinline__ int tile_of(int rsx, int rsy) {
    // window [rsx, rsx+4] always fits tile [tx*32-2, tx*32+33]
    int tx = (rsx + HALO) >> TSH;
    int ty = (rsy + HALO) >> TSH;
    return tx * NTY + ty;
}

// ---------- phase 1: per-(tile,block) counts, tile-major ----------
__global__ __launch_bounds__(1024) void count_kernel(
    const float* __restrict__ pos, int* __restrict__ counts, int n, int B1)
{
    __shared__ int hist[NT];
    for (int t = threadIdx.x; t < NT; t += 1024) hist[t] = 0;
    __syncthreads();
    int i = blockIdx.x * 1024 + threadIdx.x;
    if (i < n) {
        float x = pos[i], y = pos[n + i];
        int rsx = min(max((int)floorf(x - 2.0f), 0), NBX - KNB);
        int rsy = min(max((int)floorf(y - 2.0f), 0), NBY - KNB);
        atomicAdd(&hist[tile_of(rsx, rsy)], 1);
    }
    __syncthreads();
    for (int t = threadIdx.x; t < NT; t += 1024)
        counts[t * B1 + blockIdx.x] = hist[t];
}

// ---------- phase 2: exclusive scan of counts (chunked) ----------
__global__ __launch_bounds__(256) void scan1_kernel(
    const int* __restrict__ counts, int* __restrict__ base,
    int* __restrict__ partials, int L)
{
    __shared__ int ls[256];
    int tid = threadIdx.x;
    int i0 = blockIdx.x * 1024 + tid * 4;
    int v[4], s = 0;
#pragma unroll
    for (int k = 0; k < 4; ++k) { v[k] = (i0 + k < L) ? counts[i0 + k] : 0; s += v[k]; }
    ls[tid] = s;
    __syncthreads();
    for (int off = 1; off < 256; off <<= 1) {
        int t = (tid >= off) ? ls[tid - off] : 0;
        __syncthreads();
        ls[tid] += t;
        __syncthreads();
    }
    int excl = ls[tid] - s;
    int run = excl;
#pragma unroll
    for (int k = 0; k < 4; ++k) { if (i0 + k < L) base[i0 + k] = run; run += v[k]; }
    if (tid == 255) partials[blockIdx.x] = ls[255];
}

__global__ __launch_bounds__(256) void scan2_kernel(int* __restrict__ partials, int G)
{
    __shared__ int ls[256];
    int tid = threadIdx.x;
    int i0 = tid * 4;
    int v[4], s = 0;
#pragma unroll
    for (int k = 0; k < 4; ++k) { v[k] = (i0 + k < G) ? partials[i0 + k] : 0; s += v[k]; }
    ls[tid] = s;
    __syncthreads();
    for (int off = 1; off < 256; off <<= 1) {
        int t = (tid >= off) ? ls[tid - off] : 0;
        __syncthreads();
        ls[tid] += t;
        __syncthreads();
    }
    int excl = ls[tid] - s;
    int run = excl;
#pragma unroll
    for (int k = 0; k < 4; ++k) { if (i0 + k < G) partials[i0 + k] = run; run += v[k]; }
}

// ---------- phase 3: tile-sorted scatter of records ----------
// PAYLOAD: record = 12 floats {startx, starty, px[5], py[5]}; else 1 int node idx.
template <bool PAYLOAD>
__global__ __launch_bounds__(1024) void scatter_kernel(
    const float* __restrict__ pos,
    const float* __restrict__ nsx, const float* __restrict__ nsy,
    const float* __restrict__ axp, const float* __restrict__ bxp, const float* __restrict__ cxp,
    const float* __restrict__ ayp, const float* __restrict__ byp, const float* __restrict__ cyp,
    const int* __restrict__ base, const int* __restrict__ partials,
    float* __restrict__ records, int n, int B1)
{
    __shared__ int lcur[NT];
    int tid = threadIdx.x;
    for (int t = tid; t < NT; t += 1024) lcur[t] = 0;
    __syncthreads();
    int i = blockIdx.x * 1024 + tid;
    if (i >= n) return;

    float x = pos[i], y = pos[n + i];
    int rsx, rsy, tile;
    float px[KNB], py[KNB];
    if (PAYLOAD) {
        compute_node(x, y, nsx[i], nsy[i], axp[i], bxp[i], cxp[i],
                     ayp[i], byp[i], cyp[i], rsx, rsy, px, py);
    } else {
        rsx = min(max((int)floorf(x - 2.0f), 0), NBX - KNB);
        rsy = min(max((int)floorf(y - 2.0f), 0), NBY - KNB);
    }
    tile = tile_of(rsx, rsy);
    int rank = atomicAdd(&lcur[tile], 1);
    int p = tile * B1 + blockIdx.x;
    int slot = base[p] + partials[p >> 10] + rank;

    if (PAYLOAD) {
        float4* rec = (float4*)(records + (size_t)slot * 12);
        rec[0] = make_float4(__int_as_float(rsx), __int_as_float(rsy), px[0], px[1]);
        rec[1] = make_float4(px[2], px[3], px[4], py[0]);
        rec[2] = make_float4(py[1], py[2], py[3], py[4]);
    } else {
        ((int*)records)[slot] = i;
    }
}

// ---------- phase 4: per-tile LDS accumulate + coalesced writeback ----------
template <bool PAYLOAD>
__global__ __launch_bounds__(256) void accum_kernel(
    const float* __restrict__ records,
    const int* __restrict__ base, const int* __restrict__ partials,
    float* __restrict__ map, int n, int B1,
    const float* __restrict__ pos,
    const float* __restrict__ nsx, const float* __restrict__ nsy,
    const float* __restrict__ axp, const float* __restrict__ bxp, const float* __restrict__ cxp,
    const float* __restrict__ ayp, const float* __restrict__ byp, const float* __restrict__ cyp)
{
    __shared__ float lds[RWORDS];
    int tile = blockIdx.x / BPT;
    int sub  = blockIdx.x % BPT;
    int tx = tile / NTY, ty = tile % NTY;
    int tid = threadIdx.x;

    for (int w = tid; w < RWORDS; w += 256) lds[w] = 0.0f;
    __syncthreads();

    int p0 = tile * B1;
    int off0 = base[p0] + partials[p0 >> 10];
    int off1 = (tile == NT - 1) ? n : (base[p0 + B1] + partials[(p0 + B1) >> 10]);

    for (int j = off0 + sub * 256 + tid; j < off1; j += BPT * 256) {
        int rsx, rsy;
        float px[KNB], py[KNB];
        if (PAYLOAD) {
            const float4* rec = (const float4*)(records + (size_t)j * 12);
            float4 r0 = rec[0], r1 = rec[1], r2 = rec[2];
            rsx = __float_as_int(r0.x); rsy = __float_as_int(r0.y);
            px[0] = r0.z; px[1] = r0.w; px[2] = r1.x; px[3] = r1.y; px[4] = r1.z;
            py[0] = r1.w; py[1] = r2.x; py[2] = r2.y; py[3] = r2.z; py[4] = r2.w;
        } else {
            int idx = ((const int*)records)[j];
            compute_node(pos[idx], pos[n + idx], nsx[idx], nsy[idx],
                         axp[idx], bxp[idx], cxp[idx],
                         ayp[idx], byp[idx], cyp[idx], rsx, rsy, px, py);
        }
        int lx = rsx + HALO - (tx << TSH);
        int ly = rsy + HALO - (ty << TSH);
        int lbase = lx * RDIM + ly;
#pragma unroll
        for (int kx = 0; kx < KNB; ++kx) {
            float vx = px[kx];
#pragma unroll
            for (int ky = 0; ky < KNB; ++ky)
                atomicAdd(&lds[lbase + kx * RDIM + ky], vx * py[ky]);
        }
    }
    __syncthreads();

    int gx0 = (tx << TSH) - HALO, gy0 = (ty << TSH) - HALO;
    for (int w = tid; w < RWORDS; w += 256) {
        int wx = w / RDIM, wy = w - wx * RDIM;
        int gx = gx0 + wx, gy = gy0 + wy;
        float v = lds[w];
        if ((unsigned)gx < (unsigned)NBX && (unsigned)gy < (unsigned)NBY && v != 0.0f)
            atomicAdd(&map[(gx << 9) + gy], v);
    }
}

// ---------- phase 5: cost reduce ----------
__global__ __launch_bounds__(256) void cost_kernel(
    const float* __restrict__ map, const float* __restrict__ initial_map,
    float* __restrict__ out)
{
    float acc = 0.0f;
    int stride = gridDim.x * blockDim.x;
    for (int b = blockIdx.x * blockDim.x + threadIdx.x; b < NMAP; b += stride) {
        float d = map[b] + initial_map[b] - TARGET_AREA;
        acc += d * d;
    }
#pragma unroll
    for (int off = 32; off > 0; off >>= 1)
        acc += __shfl_down(acc, off, 64);
    __shared__ float smem[4];
    int lane = threadIdx.x & 63;
    int wave = threadIdx.x >> 6;
    if (lane == 0) smem[wave] = acc;
    __syncthreads();
    if (threadIdx.x == 0)
        atomicAdd(out, smem[0] + smem[1] + smem[2] + smem[3]);
}

// ---------- tier C fallback (round-1 code) ----------
__global__ __launch_bounds__(256) void fallback_scatter_kernel(
    const float* __restrict__ pos,
    const float* __restrict__ nsx, const float* __restrict__ nsy,
    const float* __restrict__ axp, const float* __restrict__ bxp, const float* __restrict__ cxp,
    const float* __restrict__ ayp, const float* __restrict__ byp, const float* __restrict__ cyp,
    float* __restrict__ map, int n)
{
    int i = blockIdx.x * blockDim.x + threadIdx.x;
    if (i >= n) return;
    int rsx, rsy;
    float px[KNB], py[KNB];
    compute_node(pos[i], pos[n + i], nsx[i], nsy[i], axp[i], bxp[i], cxp[i],
                 ayp[i], byp[i], cyp[i], rsx, rsy, px, py);
#pragma unroll
    for (int kx = 0; kx < KNB; ++kx) {
        int rowbase = (rsx + kx) * NBY + rsy;
#pragma unroll
        for (int ky = 0; ky < KNB; ++ky)
            atomicAdd(&map[rowbase + ky], px[kx] * py[ky]);
    }
}

extern "C" void kernel_launch(void* const* d_in, const int* in_sizes, int n_in,
                              void* d_out, int out_size, void* d_ws, size_t ws_size,
                              hipStream_t stream) {
    const float* pos = (const float*)d_in[0];
    const float* nsx = (const float*)d_in[1];
    const float* nsy = (const float*)d_in[2];
    const float* axp = (const float*)d_in[3];
    const float* bxp = (const float*)d_in[4];
    const float* cxp = (const float*)d_in[5];
    const float* ayp = (const float*)d_in[6];
    const float* byp = (const float*)d_in[7];
    const float* cyp = (const float*)d_in[8];
    const float* initial_map = (const float*)d_in[11];

    int n = in_sizes[1];
    int B1 = (n + 1023) >> 10;          // phase-1/3 blocks
    int L  = NT * B1;                   // counts length (tile-major)
    int G  = (L + 1023) >> 10;          // scan chunks (must be <= 1024)

    size_t off_counts = (size_t)NMAP * 4;
    size_t off_base   = off_counts + (size_t)L * 4;
    size_t off_part   = off_base + (size_t)L * 4;
    size_t off_rec    = (off_part + (size_t)G * 4 + 63) & ~(size_t)63;
    size_t need_A = off_rec + (size_t)n * 48;
    size_t need_B = off_rec + (size_t)n * 4;

    float* map      = (float*)d_ws;
    int*   counts   = (int*)((char*)d_ws + off_counts);
    int*   basep    = (int*)((char*)d_ws + off_base);
    int*   partials = (int*)((char*)d_ws + off_part);
    float* records  = (float*)((char*)d_ws + off_rec);

    hipMemsetAsync(d_out, 0, sizeof(float), stream);

    if (ws_size >= need_B && G <= 1024) {
        bool payload = (ws_size >= need_A);
        hipMemsetAsync(d_ws, 0, off_counts, stream);   // zero map only
        count_kernel<<<B1, 1024, 0, stream>>>(pos, counts, n, B1);
        scan1_kernel<<<G, 256, 0, stream>>>(counts, basep, partials, L);
        scan2_kernel<<<1, 256, 0, stream>>>(partials, G);
        if (payload) {
            scatter_kernel<true><<<B1, 1024, 0, stream>>>(
                pos, nsx, nsy, axp, bxp, cxp, ayp, byp, cyp,
                basep, partials, records, n, B1);
            accum_kernel<true><<<NT * BPT, 256, 0, stream>>>(
                records, basep, partials, map, n, B1,
                pos, nsx, nsy, axp, bxp, cxp, ayp, byp, cyp);
        } else {
            scatter_kernel<false><<<B1, 1024, 0, stream>>>(
                pos, nsx, nsy, axp, bxp, cxp, ayp, byp, cyp,
                basep, partials, records, n, B1);
            accum_kernel<false><<<NT * BPT, 256, 0, stream>>>(
                records, basep, partials, map, n, B1,
                pos, nsx, nsy, axp, bxp, cxp, ayp, byp, cyp);
        }
        cost_kernel<<<256, 256, 0, stream>>>(map, initial_map, (float*)d_out);
    } else {
        // tier C: direct atomic scatter into map in ws
        hipMemsetAsync(d_ws, 0, (size_t)NMAP * 4, stream);
        fallback_scatter_kernel<<<(n + 255) / 256, 256, 0, stream>>>(
            pos, nsx, nsy, axp, bxp, cxp, ayp, byp, cyp, map, n);
        cost_kernel<<<256, 256, 0, stream>>>(map, initial_map, (float*)d_out);
    }
}